// Round 3
// baseline (309.396 us; speedup 1.0000x reference)
//
#include <hip/hip_runtime.h>

// Problem constants (match reference)
constexpr int   T_STEPS = 64;
constexpr int   NN      = 2048;
constexpr float DT_TAU  = 0.1f;    // DT * TAU_MEM_INV
constexpr float V_TH_C  = 1.0f;
constexpr float TRC     = 0.05f;   // DT * TAU_PRE_INV == DT * TAU_POST_INV
constexpr float ETA     = 1e-3f;   // ETA_PLUS == ETA_MINUS

// 256 blocks x 512 threads (cooperative, 1 block/CU). Block b owns neurons
// [8b, 8b+8). Wave w (of 8) owns BOTH neuron 8b+w (its w-row in registers,
// v/tpo replicated across lanes) AND chunk w (neurons [256w, 256w+256) =
// source blocks [32w, 32w+32)) of the replicated z/tp LDS images.
//
// BARRIER-FREE step (round-3 restructure): no __syncthreads in the main loop.
//  a. wave computes its own LIF from register isyn (no LDS round-trip)
//  b. lane0 ds_atomic_add's (1<<24)|(z<<w) into word_s[par]: count rides in
//     the high byte, spike bits in the low byte (disjoint -> add == or).
//     The 8th arriver (old>>24 == 7) publishes IMMEDIATELY: critical path
//     from last wave's arrival to global store issue is ~50 cy (was: barrier
//     + wave-0 reschedule + ballot + LDS isyn round-trip, ~300+ cy).
//  c. lanes 0..31 poll ONLY their own chunk's 32 words (own 128B lines)
//  d. distribute words intra-wave via __shfl, unpack, update tp regs
//  e. write z/tp chunk w to LDS, RELEASE done_s[w] = k+1
//  f. consume chunks c=0..7 gated on done_s[c] >= k+1: the poll tail of
//     straggler lines OVERLAPS with compute on already-landed chunks
//  g. butterfly-reduce acc -> isyn stays in registers (all lanes)
//
// Overwrite/order safety (no barriers needed):
//  - RAW: done_s[c] released after chunk writes, acquired before reads.
//  - WAR: wave c overwrites chunk c at k+1 step e only after polling tag k+2,
//    which requires publish(k+1), which requires ALL waves' arrival at k+1,
//    which follows their step f/g of k (done reading chunk c).
//  - zpub slot (par,b) written with tag k+3 only after publish(k+2)'s gating
//    chain passes through every wave of every block consuming tag k+1 -> a
//    poller spinning for tag k+1 can never miss it ('!=' loop is safe).
//  - word_s[par] reset by the publisher of k is ordered before any arrival
//    at k+2 via: reset -> (program order) publisher's done release at k ->
//    ... -> publish(k+1) -> polls(k+2 tag) -> arrivals(k+2).
//  - Numerics bit-identical to the previous passing kernel: same per-lane
//    accumulation order (c = 0..7, x/y/z/w), same expression forms.
constexpr int BLOCKS  = 256;
constexpr int THREADS = 512;
constexpr int ROWS_PER_BLOCK = NN / BLOCKS;   // 8 == waves per block
constexpr int CHUNKS = NN / 256;              // 8 float4 chunks per lane

__global__ __launch_bounds__(THREADS)
void snn_msg_kernel(const float* __restrict__ x,       // [T, N]
                    const float* __restrict__ w_in,    // [N, N] pristine (never written)
                    const float* __restrict__ tpre0,   // [N]
                    const float* __restrict__ tpost0,  // [N]
                    unsigned long long* __restrict__ zpub, // [2][BLOCKS*stride]
                    int stride,                        // u64 units between words
                    float*       __restrict__ out)     // [T, N] spikes
{
    const int bid  = blockIdx.x;
    const int tid  = threadIdx.x;
    const int wv   = tid >> 6;
    const int lane = tid & 63;
    const int row  = bid * ROWS_PER_BLOCK + wv;   // this wave's neuron / w row

    __shared__ __align__(16) float z_s[NN];       // replicated spike vector
    __shared__ __align__(16) float tp_s[NN];      // replicated pre-trace
    __shared__ __align__(16) float x_s[T_STEPS * ROWS_PER_BLOCK]; // owned inputs
    __shared__ int      done_s[CHUNKS];           // chunk-ready flags (monotone k+1)
    __shared__ unsigned word_s[2];                // [parity] count<<24 | bits

    // Replicated tp in registers (neurons 4*tid..4*tid+3). No LDS mirror
    // needed at init: tp_s/z_s are write-before-read each step (done-gated).
    float4 tp4 = ((const float4*)tpre0)[tid];

    // Stage ALL owned inputs x[t][8b..8b+8) into LDS once.
    x_s[tid] = x[(size_t)(tid >> 3) * NN + bid * ROWS_PER_BLOCK + (tid & 7)];

    if (tid < CHUNKS) done_s[tid] = 0;
    if (tid < 2)      word_s[tid] = 0u;

    // Own-neuron state, replicated across all 64 lanes (redundant scalar ops
    // beat cross-lane traffic). tpost0[row] is a broadcast load.
    float v_own   = 0.0f;
    float tpo_own = tpost0[row];

    // This wave's w row into registers: chunk c holds w[row][(c*64+lane)*4 ..+3].
    const float4* wrow4 = (const float4*)(w_in + (size_t)row * NN);
    float4 wreg[CHUNKS];
    #pragma unroll
    for (int c = 0; c < CHUNKS; ++c) wreg[c] = wrow4[c * 64 + lane];

    float isyn = 0.0f;                 // w @ z carry, lives in registers
    __syncthreads();                   // the ONLY block barrier (init)

    for (int k = 0; k < T_STEPS; ++k) {
        const int par = k & 1;

        // ---- a: LIF for own neuron (all lanes redundantly) ----
        float xk = x_s[k * ROWS_PER_BLOCK + wv];
        float v  = v_own + DT_TAU * ((0.0f - v_own) + isyn + xk);
        float z  = (v - V_TH_C > 0.0f) ? 1.0f : 0.0f;
        v_own    = v * (1.0f - z);
        tpo_own  = tpo_own + TRC * (-tpo_own + z);
        if (lane == 0) out[(size_t)k * NN + row] = z;   // fire-and-forget raster
        if (k == T_STEPS - 1) break;   // raster[63] written; no exchange needed

        // ---- b: arrive; 8th wave publishes immediately ----
        if (lane == 0) {
            unsigned add = 0x01000000u | (z > 0.0f ? (1u << wv) : 0u);
            unsigned old = __hip_atomic_fetch_add(&word_s[par], add,
                               __ATOMIC_RELAXED, __HIP_MEMORY_SCOPE_WORKGROUP);
            if ((old >> 24) == 7u) {
                unsigned bits = (old + add) & 0xFFu;
                // reset BEFORE publish: ordered to same addr after the RMW;
                // visible to k+2 arrivals via the done/publish gating chain.
                __hip_atomic_store(&word_s[par], 0u,
                                   __ATOMIC_RELAXED, __HIP_MEMORY_SCOPE_WORKGROUP);
                unsigned long long wrd =
                    ((unsigned long long)(unsigned)(k + 1) << 32) | bits;
                __hip_atomic_store(&zpub[(size_t)(par * BLOCKS + bid) * stride],
                                   wrd, __ATOMIC_RELAXED, __HIP_MEMORY_SCOPE_AGENT);
            }
        }

        // ---- c: poll own chunk's 32 words (lanes 0..31, own 128B lines) ----
        unsigned my_bits = 0u;
        if (lane < 32) {
            const unsigned long long* p =
                &zpub[(size_t)(par * BLOCKS + (wv * 32 + lane)) * stride];
            unsigned long long pv = __hip_atomic_load(p, __ATOMIC_RELAXED,
                                        __HIP_MEMORY_SCOPE_AGENT);
            while ((unsigned)(pv >> 32) != (unsigned)(k + 1)) {
                __builtin_amdgcn_s_sleep(1);   // ~64cy backoff
                pv = __hip_atomic_load(p, __ATOMIC_RELAXED,
                                       __HIP_MEMORY_SCOPE_AGENT);
            }
            my_bits = (unsigned)pv;
        }

        // ---- d: intra-wave distribute + unpack + tp register update ----
        // thread covers neurons [4*tid, 4*tid+4): source block = 32*wv+(lane>>1),
        // polled by lane (lane>>1); nibble (lane&1)*4 of that word.
        unsigned wbits = (unsigned)__shfl((int)my_bits, lane >> 1, 64);
        int sh = (lane & 1) * 4;
        float4 z4;
        z4.x = ((wbits >> (sh + 0)) & 1u) ? 1.0f : 0.0f;
        z4.y = ((wbits >> (sh + 1)) & 1u) ? 1.0f : 0.0f;
        z4.z = ((wbits >> (sh + 2)) & 1u) ? 1.0f : 0.0f;
        z4.w = ((wbits >> (sh + 3)) & 1u) ? 1.0f : 0.0f;
        tp4.x = tp4.x + TRC * (-tp4.x + z4.x);
        tp4.y = tp4.y + TRC * (-tp4.y + z4.y);
        tp4.z = tp4.z + TRC * (-tp4.z + z4.z);
        tp4.w = tp4.w + TRC * (-tp4.w + z4.w);

        // ---- e: write own chunk, release its flag ----
        ((float4*)z_s)[tid]  = z4;
        ((float4*)tp_s)[tid] = tp4;
        if (lane == 0)
            __hip_atomic_store(&done_s[wv], k + 1,
                               __ATOMIC_RELEASE, __HIP_MEMORY_SCOPE_WORKGROUP);

        // ---- f: fused STDP w-update + matvec, chunk-streamed ----
        // Fixed c=0..7 order keeps accumulation bit-identical to the passing
        // kernel. Do not refactor into FMA (rounding would drift w).
        const float zi_own = z;          // own neuron's spike (post side)
        const float tpoi   = tpo_own;    // own neuron's post-trace
        float acc = 0.0f;
        const float4* z4s  = (const float4*)z_s;
        const float4* tp4s = (const float4*)tp_s;
        #pragma unroll
        for (int c = 0; c < CHUNKS; ++c) {
            if (c != wv) {
                while (__hip_atomic_load(&done_s[c], __ATOMIC_ACQUIRE,
                                         __HIP_MEMORY_SCOPE_WORKGROUP) < k + 1) {}
            }
            float4 zj = z4s[c * 64 + lane];
            float4 tj = tp4s[c * 64 + lane];
            float nw;
            nw = wreg[c].x + (ETA * (zi_own * tj.x) - ETA * (tpoi * zj.x));
            nw = fminf(fmaxf(nw, 0.0f), 1.0f); wreg[c].x = nw; acc += nw * zj.x;
            nw = wreg[c].y + (ETA * (zi_own * tj.y) - ETA * (tpoi * zj.y));
            nw = fminf(fmaxf(nw, 0.0f), 1.0f); wreg[c].y = nw; acc += nw * zj.y;
            nw = wreg[c].z + (ETA * (zi_own * tj.z) - ETA * (tpoi * zj.z));
            nw = fminf(fmaxf(nw, 0.0f), 1.0f); wreg[c].z = nw; acc += nw * zj.z;
            nw = wreg[c].w + (ETA * (zi_own * tj.w) - ETA * (tpoi * zj.w));
            nw = fminf(fmaxf(nw, 0.0f), 1.0f); wreg[c].w = nw; acc += nw * zj.w;
        }

        // ---- g: butterfly reduce -> isyn in registers (all lanes) ----
        #pragma unroll
        for (int m = 32; m >= 1; m >>= 1) acc += __shfl_xor(acc, m, 64);
        isyn = acc;
    }
}

extern "C" void kernel_launch(void* const* d_in, const int* in_sizes, int n_in,
                              void* d_out, int out_size, void* d_ws, size_t ws_size,
                              hipStream_t stream) {
    const float* x     = (const float*)d_in[0];   // [T,N]
    const float* w_in  = (const float*)d_in[1];   // [N,N]
    const float* tpre  = (const float*)d_in[2];   // [N]
    const float* tpost = (const float*)d_in[3];   // [N]
    float*       out   = (float*)d_out;           // [T,N]

    unsigned long long* zpub = (unsigned long long*)d_ws;

    // Pad each published word to its own line if the workspace allows:
    // 128B stride (TCC line) needs 64KB, 64B needs 32KB, else packed (4KB).
    int stride;
    if      (ws_size >= (size_t)2 * BLOCKS * 16 * sizeof(unsigned long long)) stride = 16;
    else if (ws_size >= (size_t)2 * BLOCKS *  8 * sizeof(unsigned long long)) stride = 8;
    else                                                                      stride = 1;

    void* args[] = {(void*)&x, (void*)&w_in, (void*)&tpre, (void*)&tpost,
                    (void*)&zpub, (void*)&stride, (void*)&out};
    hipLaunchCooperativeKernel((void*)snn_msg_kernel,
                               dim3(BLOCKS), dim3(THREADS),
                               args, 0, stream);
}

// Round 4
// 264.417 us; speedup vs baseline: 1.1701x; 1.1701x over previous
//
#include <hip/hip_runtime.h>

// Problem constants (match reference)
constexpr int   T_STEPS = 64;
constexpr int   NN      = 2048;
constexpr float DT_TAU  = 0.1f;    // DT * TAU_MEM_INV
constexpr float V_TH_C  = 1.0f;
constexpr float TRC     = 0.05f;   // DT * TAU_PRE_INV == DT * TAU_POST_INV
constexpr float ETA     = 1e-3f;   // ETA_PLUS == ETA_MINUS

// 256 blocks x 512 threads (cooperative, 1 block/CU). Block b owns neurons
// [8b, 8b+8); wave w owns neuron 8b+w (w-row in 32 VGPR/lane; v/tpo/isyn
// replicated across its 64 lanes — redundant scalar ops beat cross-lane
// traffic). z/tp replicated per block in LDS, rebuilt each step from the
// published spike words.
//
// Step k (round-4 structure = round-2 barrier skeleton + early publish):
//  a. (all waves) LIF from register isyn -> z; update v,tpo in regs; lane0
//     writes raster + ds-atomic arrive on word_s[par]: add (1<<24)|(z<<w).
//     The 8TH ARRIVER publishes immediately: one tagged u64 ((k+1)<<32|bits)
//     to this block's own 128B line (round-2 result: padding words to private
//     lines removed MALL queuing, 244->203 us). Publish fires ~50cy after the
//     LAST wave's butterfly, replacing round-2's barrier + wave-0 wakeup +
//     LDS-isyn read + ballot (~300+cy).
//  b. pollers tid<256 spin on word tid (tag k+1), then unpack ALL 8 of that
//     word's neurons straight into z_s and RMW tp_s (tp_s[8t..8t+8) is
//     touched only by poller t -> exclusive, bit-identical update order).
//     No zw_s round-trip, no shfl distribute.
//     __syncthreads  (RAW: b-writes visible before C-reads)
//  c. fused STDP w-update (regs) + matvec; butterfly -> isyn in regs;
//     prefetch next x into a register.
//     __syncthreads  (WAR: all C-reads of z_s/tp_s complete before any
//                     poller's next b-write; also orders word_s reset (a)
//                     before the k+2 arrivals that reuse that parity slot)
//
// Why both barriers are kept: round 3 removed them and (a) regressed 203->224
// (done-flag streaming serialized the waves), (b) its WAR argument bottomed
// out at remote blocks seeing our ARRIVAL, not our read-completion — timing
// margin, not happens-before. Two barriers is the sound minimum here.
//
// Cross-block safety (unchanged from round 2): message==data (bits travel in
// the tagged word, single 8B atomic); tag 1..64 never matches 0x00/0xAA
// poison; parity double-buffer + the publish gating chain (publish(k+2) on
// any block transitively requires every block's pollers to have consumed tag
// k+1) -> '!=' spin can never miss its tag; no ws init needed.
constexpr int BLOCKS  = 256;
constexpr int THREADS = 512;
constexpr int ROWS_PER_BLOCK = NN / BLOCKS;   // 8 == waves per block
constexpr int CHUNKS = NN / 256;              // 8 float4 chunks per lane

__global__ __launch_bounds__(THREADS)
void snn_msg_kernel(const float* __restrict__ x,       // [T, N]
                    const float* __restrict__ w_in,    // [N, N] pristine (never written)
                    const float* __restrict__ tpre0,   // [N]
                    const float* __restrict__ tpost0,  // [N]
                    unsigned long long* __restrict__ zpub, // [2][BLOCKS*stride]
                    int stride,                        // u64 units between words
                    float*       __restrict__ out)     // [T, N] spikes
{
    const int bid  = blockIdx.x;
    const int tid  = threadIdx.x;
    const int wv   = tid >> 6;
    const int lane = tid & 63;
    const int row  = bid * ROWS_PER_BLOCK + wv;   // this wave's neuron / w row

    __shared__ __align__(16) float z_s[NN];       // replicated spike vector
    __shared__ __align__(16) float tp_s[NN];      // replicated pre-trace (persistent)
    __shared__ __align__(16) float x_s[T_STEPS * ROWS_PER_BLOCK]; // owned inputs
    __shared__ unsigned word_s[2];                // [parity] count<<24 | bits

    // tp_s initialized from tpre0; thereafter RMW'd in LDS by its poller.
    ((float4*)tp_s)[tid] = ((const float4*)tpre0)[tid];

    // Stage ALL owned inputs x[t][8b..8b+8) into LDS once.
    x_s[tid] = x[(size_t)(tid >> 3) * NN + bid * ROWS_PER_BLOCK + (tid & 7)];

    if (tid < 2) word_s[tid] = 0u;

    // Own-neuron state, replicated across all 64 lanes.
    float v_own   = 0.0f;
    float tpo_own = tpost0[row];          // broadcast load

    // This wave's w row: chunk c holds w[row][(c*64+lane)*4 ..+3].
    const float4* wrow4 = (const float4*)(w_in + (size_t)row * NN);
    float4 wreg[CHUNKS];
    #pragma unroll
    for (int c = 0; c < CHUNKS; ++c) wreg[c] = wrow4[c * 64 + lane];

    float isyn = 0.0f;                    // w @ z carry, lives in registers
    float xk   = 0.0f;                    // prefetched input current
    __syncthreads();
    xk = x_s[wv];                         // x[0][row] (post-barrier: x_s ready)

    for (int k = 0; k < T_STEPS; ++k) {
        const int par = k & 1;

        // ---- a: LIF (all lanes redundantly); lane0 raster + arrive/publish ----
        float v = v_own + DT_TAU * ((0.0f - v_own) + isyn + xk);
        float z = (v - V_TH_C > 0.0f) ? 1.0f : 0.0f;
        v_own   = v * (1.0f - z);
        tpo_own = tpo_own + TRC * (-tpo_own + z);   // post-trace (post-update
                                                    // value feeds C, as in ref)
        if (lane == 0) {
            out[(size_t)k * NN + row] = z;          // fire-and-forget raster
            if (k + 1 < T_STEPS) {
                unsigned add = 0x01000000u | (z > 0.0f ? (1u << wv) : 0u);
                unsigned old = __hip_atomic_fetch_add(&word_s[par], add,
                                   __ATOMIC_RELAXED, __HIP_MEMORY_SCOPE_WORKGROUP);
                if ((old >> 24) == 7u) {            // 8th arriver publishes
                    unsigned bits = (old + add) & 0xFFu;
                    // reset for reuse at k+2; ordered before k+2 arrivals by
                    // the post-C barriers of iterations k and k+1.
                    __hip_atomic_store(&word_s[par], 0u,
                                       __ATOMIC_RELAXED, __HIP_MEMORY_SCOPE_WORKGROUP);
                    unsigned long long wrd =
                        ((unsigned long long)(unsigned)(k + 1) << 32) | bits;
                    __hip_atomic_store(&zpub[(size_t)(par * BLOCKS + bid) * stride],
                                       wrd, __ATOMIC_RELAXED,
                                       __HIP_MEMORY_SCOPE_AGENT);
                }
            }
        }
        if (k == T_STEPS - 1) break;   // raster[63] written; no exchange needed

        // ---- b: poller tid polls word tid (own 128B line), unpacks in place ----
        if (tid < BLOCKS) {
            const unsigned long long* p =
                &zpub[(size_t)(par * BLOCKS + tid) * stride];
            unsigned long long pv = __hip_atomic_load(p, __ATOMIC_RELAXED,
                                        __HIP_MEMORY_SCOPE_AGENT);
            while ((unsigned)(pv >> 32) != (unsigned)(k + 1)) {
                __builtin_amdgcn_s_sleep(1);   // ~64cy backoff
                pv = __hip_atomic_load(p, __ATOMIC_RELAXED,
                                       __HIP_MEMORY_SCOPE_AGENT);
            }
            const unsigned bits = (unsigned)pv;   // z of neurons 8*tid..8*tid+7
            float4 z0, z1;
            z0.x = (bits & 0x01u) ? 1.0f : 0.0f;
            z0.y = (bits & 0x02u) ? 1.0f : 0.0f;
            z0.z = (bits & 0x04u) ? 1.0f : 0.0f;
            z0.w = (bits & 0x08u) ? 1.0f : 0.0f;
            z1.x = (bits & 0x10u) ? 1.0f : 0.0f;
            z1.y = (bits & 0x20u) ? 1.0f : 0.0f;
            z1.z = (bits & 0x40u) ? 1.0f : 0.0f;
            z1.w = (bits & 0x80u) ? 1.0f : 0.0f;
            float4* zp  = ((float4*)z_s)  + tid * 2;
            float4* tpp = ((float4*)tp_s) + tid * 2;
            float4 t0 = tpp[0], t1 = tpp[1];
            // identical per-element expression as always -> bit-exact
            t0.x = t0.x + TRC * (-t0.x + z0.x);
            t0.y = t0.y + TRC * (-t0.y + z0.y);
            t0.z = t0.z + TRC * (-t0.z + z0.z);
            t0.w = t0.w + TRC * (-t0.w + z0.w);
            t1.x = t1.x + TRC * (-t1.x + z1.x);
            t1.y = t1.y + TRC * (-t1.y + z1.y);
            t1.z = t1.z + TRC * (-t1.z + z1.z);
            t1.w = t1.w + TRC * (-t1.w + z1.w);
            zp[0]  = z0; zp[1]  = z1;
            tpp[0] = t0; tpp[1] = t1;
        }
        __syncthreads();               // RAW: b-writes -> C-reads

        // ---- c: fused STDP w-update + matvec (bit-exact order: c=0..7, xyzw) ----
        // Do not refactor into FMA (rounding would drift w, can flip spikes).
        const float zi_own = z;        // own neuron's spike (== z_s[row])
        const float tpoi   = tpo_own;  // own neuron's post-trace
        xk = x_s[(k + 1) * ROWS_PER_BLOCK + wv];   // prefetch next input
        float acc = 0.0f;
        const float4* z4s  = (const float4*)z_s;
        const float4* tp4s = (const float4*)tp_s;
        #pragma unroll
        for (int c = 0; c < CHUNKS; ++c) {
            float4 zj = z4s[c * 64 + lane];
            float4 tj = tp4s[c * 64 + lane];
            float nw;
            nw = wreg[c].x + (ETA * (zi_own * tj.x) - ETA * (tpoi * zj.x));
            nw = fminf(fmaxf(nw, 0.0f), 1.0f); wreg[c].x = nw; acc += nw * zj.x;
            nw = wreg[c].y + (ETA * (zi_own * tj.y) - ETA * (tpoi * zj.y));
            nw = fminf(fmaxf(nw, 0.0f), 1.0f); wreg[c].y = nw; acc += nw * zj.y;
            nw = wreg[c].z + (ETA * (zi_own * tj.z) - ETA * (tpoi * zj.z));
            nw = fminf(fmaxf(nw, 0.0f), 1.0f); wreg[c].z = nw; acc += nw * zj.z;
            nw = wreg[c].w + (ETA * (zi_own * tj.w) - ETA * (tpoi * zj.w));
            nw = fminf(fmaxf(nw, 0.0f), 1.0f); wreg[c].w = nw; acc += nw * zj.w;
        }
        #pragma unroll
        for (int m = 32; m >= 1; m >>= 1) acc += __shfl_xor(acc, m, 64);
        isyn = acc;                    // i_syn for step k+1, in registers

        __syncthreads();               // WAR: C-reads -> next b-writes
    }
}

extern "C" void kernel_launch(void* const* d_in, const int* in_sizes, int n_in,
                              void* d_out, int out_size, void* d_ws, size_t ws_size,
                              hipStream_t stream) {
    const float* x     = (const float*)d_in[0];   // [T,N]
    const float* w_in  = (const float*)d_in[1];   // [N,N]
    const float* tpre  = (const float*)d_in[2];   // [N]
    const float* tpost = (const float*)d_in[3];   // [N]
    float*       out   = (float*)d_out;           // [T,N]

    unsigned long long* zpub = (unsigned long long*)d_ws;

    // Pad each published word to its own line if the workspace allows:
    // 128B stride (TCC line) needs 64KB, 64B needs 32KB, else packed (4KB).
    int stride;
    if      (ws_size >= (size_t)2 * BLOCKS * 16 * sizeof(unsigned long long)) stride = 16;
    else if (ws_size >= (size_t)2 * BLOCKS *  8 * sizeof(unsigned long long)) stride = 8;
    else                                                                      stride = 1;

    void* args[] = {(void*)&x, (void*)&w_in, (void*)&tpre, (void*)&tpost,
                    (void*)&zpub, (void*)&stride, (void*)&out};
    hipLaunchCooperativeKernel((void*)snn_msg_kernel,
                               dim3(BLOCKS), dim3(THREADS),
                               args, 0, stream);
}